// Round 12
// baseline (200.300 us; speedup 1.0000x reference)
//
#include <hip/hip_runtime.h>
#include <math.h>

// Problem constants
#define MROWS   16384      // B*N
#define KCODES  8192
#define CDIM    256

// d_out layout (floats): [quantized 4194304][loss 1][indices 16384]
#define LOSS_OFF 4194304
#define IDXOFF   4194305

// ---- ws byte layout (~13.8 MB) ----
#define NSPLIT  8
#define WS_EF   0                            // f16 E plane, FRAGMENT order, 4 MB
#define WS_ZF   (WS_EF + KCODES * CDIM * 2)  // f16 z plane, FRAGMENT order, 8.4 MB
#define WS_EN   (WS_ZF + MROWS * CDIM * 2)   // float[8192] ||e||^2 + 1024 bias
#define WS_PI   (WS_EN + KCODES * 4)         // int[NSPLIT*MROWS] split winner idx
#define WS_PD   (WS_PI + NSPLIT * MROWS * 4) // float[NSPLIT*MROWS] winner approx dist

#define CODES_PER_SPLIT (KCODES / NSPLIT)    // 1024
#define STEPS64 (CODES_PER_SPLIT / 64)       // 16 steps of 64 codes

typedef float    v4f __attribute__((ext_vector_type(4)));
typedef _Float16 v8h __attribute__((ext_vector_type(8)));
typedef __attribute__((address_space(1))) const unsigned int gu32;
typedef __attribute__((address_space(3))) unsigned int su32;

// ---------------------------------------------------------------------------
// Kernel 1 — ROUND-12: COALESCED fragment-plane writes. The old conv wrote
// 16 B at 256 B stride (one partial line per store -> RFO + writeback
// amplification ~8x on 12.4 MB). Now each 512-thread block owns ONE 16-row
// fragment tile (8 KB): coalesced float4 reads -> f16 cvt -> LDS transpose
// (slot c*16+r) -> barrier -> thread t stores slot t: the tile goes out as
// 8 KB of full contiguous lines.
// Fragment order within tile J = j>>4: byte off = c*256 + (j&15)*16,
// c = 16B-unit of K — identical plane layout to before, only the writer
// pattern changed. en is PRE-BIASED by +1024: every pass1 score
// s = en+1024-2*z.e lies in [512,131072) -> float bits are an
// order-preserving key with constant top 6 bits (17) -> reconstructible.
// Grid: 1024 z-tiles + 512 emb-tiles = 1536 blocks x 512 thr.
__global__ __launch_bounds__(512)
void conv_kernel(const float* __restrict__ z,
                 const float* __restrict__ emb,
                 char* __restrict__ ws,
                 float* __restrict__ loss_slot) {
    __shared__ v8h tile[512];
    int t   = threadIdx.x;        // 0..511
    int bid = blockIdx.x;         // 0..1535
    bool isE = (bid >= 1024);
    int J    = isE ? (bid - 1024) : bid;   // 16-row tile index
    int rloc = t >> 5;                     // row within tile, 0..15
    int c    = t & 31;                     // 16B-unit of K, 0..31

    int j = J * 16 + rloc;
    const float* src = (isE ? emb : z) + (size_t)j * CDIM + c * 8;
    float4 a = *(const float4*)src;
    float4 b = *(const float4*)(src + 4);
    v8h h;
    h[0] = (_Float16)a.x; h[1] = (_Float16)a.y;
    h[2] = (_Float16)a.z; h[3] = (_Float16)a.w;
    h[4] = (_Float16)b.x; h[5] = (_Float16)b.y;
    h[6] = (_Float16)b.z; h[7] = (_Float16)b.w;
    tile[c * 16 + rloc] = h;

    if (isE) {
        float s = a.x * a.x + a.y * a.y + a.z * a.z + a.w * a.w +
                  b.x * b.x + b.y * b.y + b.z * b.z + b.w * b.w;
        // row j's 32 chunk-threads are contiguous lanes -> width-32 reduce
#pragma unroll
        for (int m = 1; m <= 16; m <<= 1) s += __shfl_xor(s, m, 32);
        if (c == 0) ((float*)(ws + WS_EN))[j] = s + 1024.0f;   // pre-biased
    }
    __syncthreads();

    _Float16* plane = (_Float16*)(ws + (isE ? WS_EF : WS_ZF));
    // slot t holds fragment (c'=t>>4, r'=t&15) -> byte (c'*256 + r'*16) = t*16
    *(v8h*)(plane + (size_t)J * 4096 + t * 8) = tile[t];

    if (bid == 0 && t == 0) *loss_slot = 0.f;
}

// ---------------------------------------------------------------------------
// Kernel 2: f16 MFMA distance pass — ROUND-9 WINNER VERBATIM (73 us, best
// measured; r10/r11 residency experiments reverted — allocator remats zf
// regardless of bounds/pins, and time follows 69 us + 0.25 us x barriers).
// 64 rows/wave, 256 rows/block, grid 512; 64 codes/step, 2 x 32 KB LDS
// dbuf, 16 drain barriers. sp = b&7 pins one 0.5 MB ef split per XCD.
// Argmin: packed key (float_bits(s)<<6 | st*4+ct), order-preserving exact;
// epilogue also writes the winner's reconstructed approx distance.
__global__ __launch_bounds__(256, 2)
void vq_pass1_kernel(const char* __restrict__ ws_c, char* __restrict__ ws) {
    __shared__ __attribute__((aligned(16))) char bbuf[2][32768];
    int tid  = threadIdx.x;
    int lane = tid & 63;
    int w    = tid >> 6;
    int tm   = lane & 15;         // MFMA m/n lane index
    int q    = lane >> 4;         // MFMA k-quad

    int b  = blockIdx.x;
    int sp = b & 7;               // code split == XCD (round-robin dispatch)
    int rb = b >> 3;              // row block (256 rows), 0..63
    int r0 = rb * 256 + w * 64;   // this wave's 64 rows

    // ---- prologue: load A-fragments (64 rows x full K) from zf plane ----
    const _Float16* zf_g = (const _Float16*)(ws_c + WS_ZF);
    v8h zf[4][8];
#pragma unroll
    for (int mi = 0; mi < 4; ++mi) {
        const _Float16* zr = zf_g + (size_t)((r0 >> 4) + mi) * 4096 + q * 128 + tm * 8;
#pragma unroll
        for (int kc = 0; kc < 8; ++kc)
            zf[mi][kc] = *(const v8h*)(zr + kc * 512);
    }

    const char*  efb  = ws_c + WS_EF + (size_t)(sp * 64) * 8192;  // split base
    const float* en_g = (const float*)(ws_c + WS_EN);

    // stage step st (32 KB = 64 codes) into bbuf[bi]: wave w covers bytes
    // [w*8192, w*8192+8192) as 8 x (64 lanes x 16 B) global_load_lds.
    // LDS dest is wave-uniform base + lane*16 (linear), matching the source.
#define STAGE(st, bi) do {                                                      \
        const char* g0 = efb + (size_t)(st) * 32768 + w * 8192 + lane * 16;     \
        char* l0 = &bbuf[bi][w * 8192];                                         \
        __builtin_amdgcn_global_load_lds((gu32*)g0, (su32*)l0, 16, 0, 0);       \
        __builtin_amdgcn_global_load_lds((gu32*)(g0 + 1024),                    \
                                         (su32*)(l0 + 1024), 16, 0, 0);         \
        __builtin_amdgcn_global_load_lds((gu32*)(g0 + 2048),                    \
                                         (su32*)(l0 + 2048), 16, 0, 0);         \
        __builtin_amdgcn_global_load_lds((gu32*)(g0 + 3072),                    \
                                         (su32*)(l0 + 3072), 16, 0, 0);         \
        __builtin_amdgcn_global_load_lds((gu32*)(g0 + 4096),                    \
                                         (su32*)(l0 + 4096), 16, 0, 0);         \
        __builtin_amdgcn_global_load_lds((gu32*)(g0 + 5120),                    \
                                         (su32*)(l0 + 5120), 16, 0, 0);         \
        __builtin_amdgcn_global_load_lds((gu32*)(g0 + 6144),                    \
                                         (su32*)(l0 + 6144), 16, 0, 0);         \
        __builtin_amdgcn_global_load_lds((gu32*)(g0 + 7168),                    \
                                         (su32*)(l0 + 7168), 16, 0, 0);         \
    } while (0)

    unsigned rk[16];
#pragma unroll
    for (int s = 0; s < 16; ++s) rk[s] = 0xFFFFFFFFu;

    STAGE(0, 0);
    __syncthreads();                          // drains vmcnt: buf0 ready

#pragma unroll 1
    for (int st = 0; st < STEPS64; ++st) {
        int cur = st & 1;
        if (st < STEPS64 - 1) STAGE(st + 1, cur ^ 1);   // issue-early prefetch

#pragma unroll
        for (int ct = 0; ct < 4; ++ct) {
            // B fragments from LDS: kc at ct*8192 + kc*1024 + q*256 + tm*16
            const char* lb = &bbuf[cur][ct * 8192 + q * 256 + tm * 16];
            v8h bf[8];
#pragma unroll
            for (int kc = 0; kc < 8; ++kc) bf[kc] = *(const v8h*)(lb + kc * 1024);
            float enc = en_g[sp * 1024 + st * 64 + ct * 16 + tm];  // L2-hit

            v4f acc[4];
#pragma unroll
            for (int mi = 0; mi < 4; ++mi)
                acc[mi] = __builtin_amdgcn_mfma_f32_16x16x32_f16(zf[mi][0], bf[0], (v4f)0.f, 0, 0, 0);
#pragma unroll
            for (int kc = 1; kc < 8; ++kc)
#pragma unroll
                for (int mi = 0; mi < 4; ++mi)
                    acc[mi] = __builtin_amdgcn_mfma_f32_16x16x32_f16(zf[mi][kc], bf[kc], acc[mi], 0, 0, 0);

            unsigned tag = (unsigned)(st * 4 + ct);
            // packed-key argmin: fmaf + lshl_or + min_u32 per value
#pragma unroll
            for (int mi = 0; mi < 4; ++mi)
#pragma unroll
                for (int r = 0; r < 4; ++r) {
                    float s = fmaf(-2.f, acc[mi][r], enc);  // >0, in [512,131072)
                    unsigned key = (__float_as_uint(s) << 6) | tag;
                    int slot = mi * 4 + r;
                    rk[slot] = key < rk[slot] ? key : rk[slot];
                }
        }
        __syncthreads();   // next buf staged + all waves done reading cur buf
    }
#undef STAGE

    // ---- reduce across the 16 column-lanes (tm); write split winner ----
    // key ties (same value, same tag) break on lower tm -> lower code,
    // matching np.argmin first-min semantics.
#pragma unroll
    for (int slot = 0; slot < 16; ++slot) {
        unsigned k = rk[slot];
        int      t_ = tm;
#pragma unroll
        for (int m = 1; m <= 8; m <<= 1) {
            unsigned k2 = __shfl_xor(k, m, 64);
            int      t2 = __shfl_xor(t_, m, 64);
            if (k2 < k || (k2 == k && t2 < t_)) { k = k2; t_ = t2; }
        }
        if (tm == 0) {
            int row = r0 + (slot >> 2) * 16 + q * 4 + (slot & 3);
            int bi  = sp * 1024 + (int)(k & 63u) * 16 + t_;
            ((int*)(ws + WS_PI))[sp * MROWS + row] = bi;
            // exact reconstruction: all scores have float bits[31:26] == 17
            ((float*)(ws + WS_PD))[sp * MROWS + row] =
                __uint_as_float((k >> 6) | (17u << 26));
        }
    }
}

// ---------------------------------------------------------------------------
// Kernel 3: PRUNED exact fp32 re-rank + gather + STE output + 1.25*MSE loss.
// ROUND-12: grid 1024 -> 4096, ONE row per wave (was 4 serial row-iters).
// The per-row chain (pi->pd->shuffle->gather->reduce->gather->store) is
// long-latency serial; 4x the waves hides it with TLP instead.
// Pruning: pass1's approx distance pd differs from (exact + row-constant)
// by only the f16 dot error (~+-0.05 worst). Candidates with
// pd > min(pd) + 0.75 cannot win -> skip their 1 KB exact gather entirely.
// The row-constant (1024 - ||z||^2) cancels in the comparison.
__global__ void rerank_out_kernel(const float* __restrict__ z,
                                  const float* __restrict__ emb,
                                  const char* __restrict__ ws,
                                  float* __restrict__ out) {
    __shared__ float wsum[4];
    const int*   pi = (const int*)(ws + WS_PI);
    const float* pd = (const float*)(ws + WS_PD);
    int tid = threadIdx.x, lane = tid & 63, w = tid >> 6;
    int g = lane >> 3, sub = lane & 7;    // candidate group, dim-slice
    const float4* e4 = (const float4*)emb;
    const float4* z4 = (const float4*)z;

    int row = blockIdx.x * 4 + w;
    int ci   = pi[g * MROWS + row];
    float pg = pd[g * MROWS + row];
    // min approx distance across the 8 groups (pg uniform within group)
    float dmin = pg;
#pragma unroll
    for (int m = 8; m <= 32; m <<= 1) dmin = fminf(dmin, __shfl_xor(dmin, m, 64));
    float s;
    if (pg <= dmin + 0.75f) {
        // exact squared distance over dims [sub*32, sub*32+32)
        s = 0.f;
#pragma unroll
        for (int j = 0; j < 8; ++j) {
            float4 ev = e4[(size_t)ci * 64 + sub * 8 + j];
            float4 zv = z4[(size_t)row * 64 + sub * 8 + j];
            float dx = ev.x - zv.x, dy = ev.y - zv.y;
            float dz = ev.z - zv.z, dw = ev.w - zv.w;
            s += dx * dx + dy * dy + dz * dz + dw * dw;
        }
    } else {
        s = 3e38f;   // pruned: cannot be the exact winner
    }
#pragma unroll
    for (int m = 1; m <= 4; m <<= 1) s += __shfl_xor(s, m, 64);
    // min over the 8 groups, lowest idx on ties (np first-min)
    float dv = s; int di = ci;
#pragma unroll
    for (int m = 8; m <= 32; m <<= 1) {
        float d2 = __shfl_xor(dv, m, 64);
        int   i2 = __shfl_xor(di, m, 64);
        if (d2 < dv || (d2 == dv && i2 < di)) { dv = d2; di = i2; }
    }
    if (lane == 0) out[IDXOFF + row] = (float)di;
    // gather winner, STE output, loss partial
    float4 qv = e4[(size_t)di * 64 + lane];
    float4 zv = z4[(size_t)row * 64 + lane];
    float dx = qv.x - zv.x, dy = qv.y - zv.y;
    float dz = qv.z - zv.z, dw = qv.w - zv.w;
    float4 o;   // match reference STE rounding: z + (q - z)
    o.x = zv.x + dx; o.y = zv.y + dy; o.z = zv.z + dz; o.w = zv.w + dw;
    ((float4*)out)[(size_t)row * 64 + lane] = o;
    float lsum = dx * dx + dy * dy + dz * dz + dw * dw;

#pragma unroll
    for (int m = 32; m >= 1; m >>= 1) lsum += __shfl_xor(lsum, m, 64);
    if (lane == 0) wsum[w] = lsum;
    __syncthreads();
    if (tid == 0)
        atomicAdd(out + LOSS_OFF,
                  (wsum[0] + wsum[1] + wsum[2] + wsum[3]) * (1.25f / 4194304.f));
}

// ---------------------------------------------------------------------------
extern "C" void kernel_launch(void* const* d_in, const int* in_sizes, int n_in,
                              void* d_out, int out_size, void* d_ws, size_t ws_size,
                              hipStream_t stream) {
    const float* z   = (const float*)d_in[0];
    const float* emb = (const float*)d_in[1];
    float* out = (float*)d_out;
    char*  ws  = (char*)d_ws;   // ~13.8 MB used

    hipLaunchKernelGGL(conv_kernel, dim3(MROWS / 16 + KCODES / 16), dim3(512),
                       0, stream, z, emb, ws, out + LOSS_OFF);
    hipLaunchKernelGGL(vq_pass1_kernel, dim3((MROWS / 256) * NSPLIT), dim3(256),
                       0, stream, ws, ws);
    hipLaunchKernelGGL(rerank_out_kernel, dim3(MROWS / 4), dim3(256),
                       0, stream, z, emb, ws, out);
}

// Round 15
// 164.676 us; speedup vs baseline: 1.2163x; 1.2163x over previous
//
#include <hip/hip_runtime.h>
#include <math.h>

// Problem constants
#define MROWS   16384      // B*N
#define KCODES  8192
#define CDIM    256

// d_out layout (floats): [quantized 4194304][loss 1][indices 16384]
#define LOSS_OFF 4194304
#define IDXOFF   4194305

// ---- ws byte layout (~13.8 MB) ----
#define NSPLIT  8
#define WS_EF   0                            // f16 E plane, FRAGMENT order, 4 MB
#define WS_ZF   (WS_EF + KCODES * CDIM * 2)  // f16 z plane, FRAGMENT order, 8.4 MB
#define WS_EN   (WS_ZF + MROWS * CDIM * 2)   // float[8192] ||e||^2 + 1024 bias
#define WS_PI   (WS_EN + KCODES * 4)         // int[NSPLIT*MROWS] split winner idx
#define WS_PD   (WS_PI + NSPLIT * MROWS * 4) // float[NSPLIT*MROWS] winner approx dist

#define CODES_PER_SPLIT (KCODES / NSPLIT)    // 1024
#define STEPS64 (CODES_PER_SPLIT / 64)       // 16 steps of 64 codes

typedef float    v4f __attribute__((ext_vector_type(4)));
typedef _Float16 v8h __attribute__((ext_vector_type(8)));
typedef __attribute__((address_space(1))) const unsigned int gu32;
typedef __attribute__((address_space(3))) unsigned int su32;

// ---------------------------------------------------------------------------
// Kernel 1: fp32 -> f16 fragment-order planes for BOTH z and E; ||e||^2.
// (r9 proven version.) Fragment order (halves):
// off = ((row>>4)*32 + chunk)*128 + (row&15)*8, chunk = 16B-unit of K.
// en is PRE-BIASED by +1024: every pass1 score s = en+1024-2*z.e lies in
// [512,131072) -> float bits are an order-preserving key with constant top
// 6 bits (17) -> exactly reconstructible for the rerank prune.
__global__ void conv_kernel(const float* __restrict__ z,
                            const float* __restrict__ emb,
                            char* __restrict__ ws,
                            float* __restrict__ loss_slot) {
    int t = blockIdx.x * 256 + threadIdx.x;   // one v8h each
    const int NZ = MROWS * 32;                // 524288 z v8h units
    const float4* s4;
    _Float16* dst;
    int j, c;
    bool isE = (t >= NZ);
    if (!isE) {
        j = t >> 5; c = t & 31;
        s4 = (const float4*)(z + (size_t)j * CDIM) + c * 2;
        dst = (_Float16*)(ws + WS_ZF);
    } else {
        int u = t - NZ;
        j = u >> 5; c = u & 31;
        s4 = (const float4*)(emb + (size_t)j * CDIM) + c * 2;
        dst = (_Float16*)(ws + WS_EF);
    }
    float4 a = s4[0], b = s4[1];
    v8h h;
    h[0] = (_Float16)a.x; h[1] = (_Float16)a.y;
    h[2] = (_Float16)a.z; h[3] = (_Float16)a.w;
    h[4] = (_Float16)b.x; h[5] = (_Float16)b.y;
    h[6] = (_Float16)b.z; h[7] = (_Float16)b.w;
    *(v8h*)(dst + ((size_t)(j >> 4) * 32 + c) * 128 + (j & 15) * 8) = h;
    if (isE) {
        float s = a.x * a.x + a.y * a.y + a.z * a.z + a.w * a.w +
                  b.x * b.x + b.y * b.y + b.z * b.z + b.w * b.w;
#pragma unroll
        for (int m = 1; m <= 16; m <<= 1) s += __shfl_xor(s, m, 64);
        if (c == 0) ((float*)(ws + WS_EN))[j] = s + 1024.0f;   // pre-biased
    }
    if (t == 0) *loss_slot = 0.f;
}

// ---------------------------------------------------------------------------
// Kernel 2: f16 MFMA distance pass — ROUND-9 WINNER VERBATIM (73 us best
// measured; r10/r11 residency attempts and r13/r14 cooperative fusion all
// reverted — the allocator remats zf regardless of bounds/pins, and fused
// grid.sync produced stale-candidate index failures twice).
// 64 rows/wave, 256 rows/block, grid 512; 64 codes/step, 2 x 32 KB LDS
// dbuf, 16 drain barriers. sp = b&7 pins one 0.5 MB ef split per XCD.
// Argmin: packed key (float_bits(s)<<6 | st*4+ct), order-preserving exact;
// epilogue also writes the winner's reconstructed approx distance.
__global__ __launch_bounds__(256, 2)
void vq_pass1_kernel(const char* __restrict__ ws_c, char* __restrict__ ws) {
    __shared__ __attribute__((aligned(16))) char bbuf[2][32768];
    int tid  = threadIdx.x;
    int lane = tid & 63;
    int w    = tid >> 6;
    int tm   = lane & 15;         // MFMA m/n lane index
    int q    = lane >> 4;         // MFMA k-quad

    int b  = blockIdx.x;
    int sp = b & 7;               // code split == XCD (round-robin dispatch)
    int rb = b >> 3;              // row block (256 rows), 0..63
    int r0 = rb * 256 + w * 64;   // this wave's 64 rows

    // ---- prologue: load A-fragments (64 rows x full K) from zf plane ----
    const _Float16* zf_g = (const _Float16*)(ws_c + WS_ZF);
    v8h zf[4][8];
#pragma unroll
    for (int mi = 0; mi < 4; ++mi) {
        const _Float16* zr = zf_g + (size_t)((r0 >> 4) + mi) * 4096 + q * 128 + tm * 8;
#pragma unroll
        for (int kc = 0; kc < 8; ++kc)
            zf[mi][kc] = *(const v8h*)(zr + kc * 512);
    }

    const char*  efb  = ws_c + WS_EF + (size_t)(sp * 64) * 8192;  // split base
    const float* en_g = (const float*)(ws_c + WS_EN);

    // stage step st (32 KB = 64 codes) into bbuf[bi]: wave w covers bytes
    // [w*8192, w*8192+8192) as 8 x (64 lanes x 16 B) global_load_lds.
    // LDS dest is wave-uniform base + lane*16 (linear), matching the source.
#define STAGE(st, bi) do {                                                      \
        const char* g0 = efb + (size_t)(st) * 32768 + w * 8192 + lane * 16;     \
        char* l0 = &bbuf[bi][w * 8192];                                         \
        __builtin_amdgcn_global_load_lds((gu32*)g0, (su32*)l0, 16, 0, 0);       \
        __builtin_amdgcn_global_load_lds((gu32*)(g0 + 1024),                    \
                                         (su32*)(l0 + 1024), 16, 0, 0);         \
        __builtin_amdgcn_global_load_lds((gu32*)(g0 + 2048),                    \
                                         (su32*)(l0 + 2048), 16, 0, 0);         \
        __builtin_amdgcn_global_load_lds((gu32*)(g0 + 3072),                    \
                                         (su32*)(l0 + 3072), 16, 0, 0);         \
        __builtin_amdgcn_global_load_lds((gu32*)(g0 + 4096),                    \
                                         (su32*)(l0 + 4096), 16, 0, 0);         \
        __builtin_amdgcn_global_load_lds((gu32*)(g0 + 5120),                    \
                                         (su32*)(l0 + 5120), 16, 0, 0);         \
        __builtin_amdgcn_global_load_lds((gu32*)(g0 + 6144),                    \
                                         (su32*)(l0 + 6144), 16, 0, 0);         \
        __builtin_amdgcn_global_load_lds((gu32*)(g0 + 7168),                    \
                                         (su32*)(l0 + 7168), 16, 0, 0);         \
    } while (0)

    unsigned rk[16];
#pragma unroll
    for (int s = 0; s < 16; ++s) rk[s] = 0xFFFFFFFFu;

    STAGE(0, 0);
    __syncthreads();                          // drains vmcnt: buf0 ready

#pragma unroll 1
    for (int st = 0; st < STEPS64; ++st) {
        int cur = st & 1;
        if (st < STEPS64 - 1) STAGE(st + 1, cur ^ 1);   // issue-early prefetch

#pragma unroll
        for (int ct = 0; ct < 4; ++ct) {
            // B fragments from LDS: kc at ct*8192 + kc*1024 + q*256 + tm*16
            const char* lb = &bbuf[cur][ct * 8192 + q * 256 + tm * 16];
            v8h bf[8];
#pragma unroll
            for (int kc = 0; kc < 8; ++kc) bf[kc] = *(const v8h*)(lb + kc * 1024);
            float enc = en_g[sp * 1024 + st * 64 + ct * 16 + tm];  // L2-hit

            v4f acc[4];
#pragma unroll
            for (int mi = 0; mi < 4; ++mi)
                acc[mi] = __builtin_amdgcn_mfma_f32_16x16x32_f16(zf[mi][0], bf[0], (v4f)0.f, 0, 0, 0);
#pragma unroll
            for (int kc = 1; kc < 8; ++kc)
#pragma unroll
                for (int mi = 0; mi < 4; ++mi)
                    acc[mi] = __builtin_amdgcn_mfma_f32_16x16x32_f16(zf[mi][kc], bf[kc], acc[mi], 0, 0, 0);

            unsigned tag = (unsigned)(st * 4 + ct);
            // packed-key argmin: fmaf + lshl_or + min_u32 per value
#pragma unroll
            for (int mi = 0; mi < 4; ++mi)
#pragma unroll
                for (int r = 0; r < 4; ++r) {
                    float s = fmaf(-2.f, acc[mi][r], enc);  // >0, in [512,131072)
                    unsigned key = (__float_as_uint(s) << 6) | tag;
                    int slot = mi * 4 + r;
                    rk[slot] = key < rk[slot] ? key : rk[slot];
                }
        }
        __syncthreads();   // next buf staged + all waves done reading cur buf
    }
#undef STAGE

    // ---- reduce across the 16 column-lanes (tm); write split winner ----
    // key ties (same value, same tag) break on lower tm -> lower code,
    // matching np.argmin first-min semantics.
#pragma unroll
    for (int slot = 0; slot < 16; ++slot) {
        unsigned k = rk[slot];
        int      t_ = tm;
#pragma unroll
        for (int m = 1; m <= 8; m <<= 1) {
            unsigned k2 = __shfl_xor(k, m, 64);
            int      t2 = __shfl_xor(t_, m, 64);
            if (k2 < k || (k2 == k && t2 < t_)) { k = k2; t_ = t2; }
        }
        if (tm == 0) {
            int row = r0 + (slot >> 2) * 16 + q * 4 + (slot & 3);
            int bi  = sp * 1024 + (int)(k & 63u) * 16 + t_;
            ((int*)(ws + WS_PI))[sp * MROWS + row] = bi;
            // exact reconstruction: all scores have float bits[31:26] == 17
            ((float*)(ws + WS_PD))[sp * MROWS + row] =
                __uint_as_float((k >> 6) | (17u << 26));
        }
    }
}

// ---------------------------------------------------------------------------
// Kernel 3: PRUNED exact fp32 re-rank + gather + STE output + 1.25*MSE loss.
// ROUND-15 addition: SINGLE-SURVIVOR FAST PATH. The prune invariant (since
// r5, always passing) is "pd > dmin + 0.75 => cannot be the exact winner"
// (0.75 >> 2x f16 dot error). Corollary: if EXACTLY ONE candidate survives,
// it IS the exact winner — skip the whole exact-distance phase (candidate
// gather + z slice reads + two shuffle-reduce chains). Exact-distance ties
// always co-survive (their pd differ by <= 2x error < 0.75), so the
// first-min tie-break path is preserved for them. The survivor test is
// wave-uniform (ballot popcount) -> no divergence.
// Geometry: r9 verbatim — grid 1024 x 256 thr, 4 serial row-iters per wave.
__global__ void rerank_out_kernel(const float* __restrict__ z,
                                  const float* __restrict__ emb,
                                  const char* __restrict__ ws,
                                  float* __restrict__ out) {
    __shared__ float wsum[4];
    const int*   pi = (const int*)(ws + WS_PI);
    const float* pd = (const float*)(ws + WS_PD);
    int tid = threadIdx.x, lane = tid & 63, w = tid >> 6;
    int g = lane >> 3, sub = lane & 7;    // candidate group, dim-slice
    const float4* e4 = (const float4*)emb;
    const float4* z4 = (const float4*)z;
    float lsum = 0.f;

#pragma unroll 1
    for (int it = 0; it < 4; ++it) {
        int row = it * 4096 + blockIdx.x * 4 + w;
        int ci   = pi[g * MROWS + row];
        float pg = pd[g * MROWS + row];
        // min approx distance across the 8 groups (pg uniform within group)
        float dmin = pg;
#pragma unroll
        for (int m = 8; m <= 32; m <<= 1) dmin = fminf(dmin, __shfl_xor(dmin, m, 64));

        bool alive = (pg <= dmin + 0.75f);
        unsigned long long mask = __ballot(alive);
        int di;
        if (__popcll(mask) == 8) {
            // exactly one surviving group (8 lanes) -> it is the exact winner
            di = __shfl(ci, __ffsll(mask) - 1, 64);
        } else {
            float s;
            if (alive) {
                // exact squared distance over dims [sub*32, sub*32+32)
                s = 0.f;
#pragma unroll
                for (int j = 0; j < 8; ++j) {
                    float4 ev = e4[(size_t)ci * 64 + sub * 8 + j];
                    float4 zv = z4[(size_t)row * 64 + sub * 8 + j];
                    float dx = ev.x - zv.x, dy = ev.y - zv.y;
                    float dz = ev.z - zv.z, dw = ev.w - zv.w;
                    s += dx * dx + dy * dy + dz * dz + dw * dw;
                }
            } else {
                s = 3e38f;   // pruned: cannot be the exact winner
            }
#pragma unroll
            for (int m = 1; m <= 4; m <<= 1) s += __shfl_xor(s, m, 64);
            // min over the 8 groups, lowest idx on ties (np first-min)
            float dv = s; di = ci;
#pragma unroll
            for (int m = 8; m <= 32; m <<= 1) {
                float d2 = __shfl_xor(dv, m, 64);
                int   i2 = __shfl_xor(di, m, 64);
                if (d2 < dv || (d2 == dv && i2 < di)) { dv = d2; di = i2; }
            }
        }
        if (lane == 0) out[IDXOFF + row] = (float)di;
        // gather winner, STE output, loss partial
        float4 qv = e4[(size_t)di * 64 + lane];
        float4 zv = z4[(size_t)row * 64 + lane];
        float dx = qv.x - zv.x, dy = qv.y - zv.y;
        float dz = qv.z - zv.z, dw = qv.w - zv.w;
        float4 o;   // match reference STE rounding: z + (q - z)
        o.x = zv.x + dx; o.y = zv.y + dy; o.z = zv.z + dz; o.w = zv.w + dw;
        ((float4*)out)[(size_t)row * 64 + lane] = o;
        lsum += dx * dx + dy * dy + dz * dz + dw * dw;
    }

#pragma unroll
    for (int m = 32; m >= 1; m >>= 1) lsum += __shfl_xor(lsum, m, 64);
    if (lane == 0) wsum[w] = lsum;
    __syncthreads();
    if (tid == 0)
        atomicAdd(out + LOSS_OFF,
                  (wsum[0] + wsum[1] + wsum[2] + wsum[3]) * (1.25f / 4194304.f));
}

// ---------------------------------------------------------------------------
extern "C" void kernel_launch(void* const* d_in, const int* in_sizes, int n_in,
                              void* d_out, int out_size, void* d_ws, size_t ws_size,
                              hipStream_t stream) {
    const float* z   = (const float*)d_in[0];
    const float* emb = (const float*)d_in[1];
    float* out = (float*)d_out;
    char*  ws  = (char*)d_ws;   // ~13.8 MB used

    hipLaunchKernelGGL(conv_kernel, dim3((MROWS + KCODES) * 32 / 256), dim3(256),
                       0, stream, z, emb, ws, out + LOSS_OFF);
    hipLaunchKernelGGL(vq_pass1_kernel, dim3((MROWS / 256) * NSPLIT), dim3(256),
                       0, stream, ws, ws);
    hipLaunchKernelGGL(rerank_out_kernel, dim3(1024), dim3(256),
                       0, stream, z, emb, ws, out);
}

// Round 17
// 162.876 us; speedup vs baseline: 1.2298x; 1.0110x over previous
//
#include <hip/hip_runtime.h>
#include <math.h>

// Problem constants
#define MROWS   16384      // B*N
#define KCODES  8192
#define CDIM    256

// d_out layout (floats): [quantized 4194304][loss 1][indices 16384]
#define LOSS_OFF 4194304
#define IDXOFF   4194305

// ---- ws byte layout (~13.8 MB) ----
#define NSPLIT  8
#define WS_EF   0                            // f16 E plane, FRAGMENT order, 4 MB
#define WS_ZF   (WS_EF + KCODES * CDIM * 2)  // f16 z plane, FRAGMENT order, 8.4 MB
#define WS_EN   (WS_ZF + MROWS * CDIM * 2)   // float[8192] ||e||^2 + 1024 bias
#define WS_PI   (WS_EN + KCODES * 4)         // int[NSPLIT*MROWS] split winner idx
#define WS_PD   (WS_PI + NSPLIT * MROWS * 4) // float[NSPLIT*MROWS] winner approx dist

#define CODES_PER_SPLIT (KCODES / NSPLIT)    // 1024
#define STEPS64 (CODES_PER_SPLIT / 64)       // 16 steps of 64 codes

typedef float    v4f __attribute__((ext_vector_type(4)));
typedef _Float16 v8h __attribute__((ext_vector_type(8)));
typedef __attribute__((address_space(1))) const unsigned int gu32;
typedef __attribute__((address_space(3))) unsigned int su32;

// ---------------------------------------------------------------------------
// Kernel 1: fp32 -> f16 fragment-order planes for BOTH z and E; ||e||^2.
// Fragment order (halves): off = ((row>>4)*32 + chunk)*128 + (row&15)*8,
// chunk = 16B-unit of K. en is PRE-BIASED by +1024: every pass1 score
// s = en+1024-2*z.e lies in [512,131072) -> float bits are an
// order-preserving key with constant top 6 bits (17) -> reconstructible.
__global__ void conv_kernel(const float* __restrict__ z,
                            const float* __restrict__ emb,
                            char* __restrict__ ws,
                            float* __restrict__ loss_slot) {
    int t = blockIdx.x * 256 + threadIdx.x;   // one v8h each
    const int NZ = MROWS * 32;                // 524288 z v8h units
    const float4* s4;
    _Float16* dst;
    int j, c;
    bool isE = (t >= NZ);
    if (!isE) {
        j = t >> 5; c = t & 31;
        s4 = (const float4*)(z + (size_t)j * CDIM) + c * 2;
        dst = (_Float16*)(ws + WS_ZF);
    } else {
        int u = t - NZ;
        j = u >> 5; c = u & 31;
        s4 = (const float4*)(emb + (size_t)j * CDIM) + c * 2;
        dst = (_Float16*)(ws + WS_EF);
    }
    float4 a = s4[0], b = s4[1];
    v8h h;
    h[0] = (_Float16)a.x; h[1] = (_Float16)a.y;
    h[2] = (_Float16)a.z; h[3] = (_Float16)a.w;
    h[4] = (_Float16)b.x; h[5] = (_Float16)b.y;
    h[6] = (_Float16)b.z; h[7] = (_Float16)b.w;
    *(v8h*)(dst + ((size_t)(j >> 4) * 32 + c) * 128 + (j & 15) * 8) = h;
    if (isE) {
        float s = a.x * a.x + a.y * a.y + a.z * a.z + a.w * a.w +
                  b.x * b.x + b.y * b.y + b.z * b.z + b.w * b.w;
#pragma unroll
        for (int m = 1; m <= 16; m <<= 1) s += __shfl_xor(s, m, 64);
        if (c == 0) ((float*)(ws + WS_EN))[j] = s + 1024.0f;   // pre-biased
    }
    if (t == 0) *loss_slot = 0.f;
}

// ---------------------------------------------------------------------------
// Kernel 2: f16 MFMA distance pass — FINAL FORM (r9 structure, best measured
// 71.8 us). Session record: occupancy x2 (r4) null; counted-vmcnt (r3/r8)
// null or regressed; VGPR residency (r7/r10/r11) unreachable — allocator
// remats/spills regardless of bounds or pins; AGPR pin via inline-asm MFMA
// (r16) broke correctness (hand asm bypasses MFMA hazard modeling);
// cooperative fusion (r13/r14) broke indices via grid.sync staleness.
// What works: barrier amortization (64 codes/step = 16 barriers), XCD-
// pinned ef split (sp=b&7), packed-key argmin, LDS B-staging via
// global_load_lds width=16.
__global__ __launch_bounds__(256, 2)
void vq_pass1_kernel(const char* __restrict__ ws_c, char* __restrict__ ws) {
    __shared__ __attribute__((aligned(16))) char bbuf[2][32768];
    int tid  = threadIdx.x;
    int lane = tid & 63;
    int w    = tid >> 6;
    int tm   = lane & 15;         // MFMA m/n lane index
    int q    = lane >> 4;         // MFMA k-quad

    int b  = blockIdx.x;
    int sp = b & 7;               // code split == XCD (round-robin dispatch)
    int rb = b >> 3;              // row block (256 rows), 0..63
    int r0 = rb * 256 + w * 64;   // this wave's 64 rows

    // ---- prologue: load A-fragments (64 rows x full K) from zf plane ----
    const _Float16* zf_g = (const _Float16*)(ws_c + WS_ZF);
    v8h zf[4][8];
#pragma unroll
    for (int mi = 0; mi < 4; ++mi) {
        const _Float16* zr = zf_g + (size_t)((r0 >> 4) + mi) * 4096 + q * 128 + tm * 8;
#pragma unroll
        for (int kc = 0; kc < 8; ++kc)
            zf[mi][kc] = *(const v8h*)(zr + kc * 512);
    }

    const char*  efb  = ws_c + WS_EF + (size_t)(sp * 64) * 8192;  // split base
    const float* en_g = (const float*)(ws_c + WS_EN);

    // stage step st (32 KB = 64 codes) into bbuf[bi]: wave w covers bytes
    // [w*8192, w*8192+8192) as 8 x (64 lanes x 16 B) global_load_lds.
    // LDS dest is wave-uniform base + lane*16 (linear), matching the source.
#define STAGE(st, bi) do {                                                      \
        const char* g0 = efb + (size_t)(st) * 32768 + w * 8192 + lane * 16;     \
        char* l0 = &bbuf[bi][w * 8192];                                         \
        __builtin_amdgcn_global_load_lds((gu32*)g0, (su32*)l0, 16, 0, 0);       \
        __builtin_amdgcn_global_load_lds((gu32*)(g0 + 1024),                    \
                                         (su32*)(l0 + 1024), 16, 0, 0);         \
        __builtin_amdgcn_global_load_lds((gu32*)(g0 + 2048),                    \
                                         (su32*)(l0 + 2048), 16, 0, 0);         \
        __builtin_amdgcn_global_load_lds((gu32*)(g0 + 3072),                    \
                                         (su32*)(l0 + 3072), 16, 0, 0);         \
        __builtin_amdgcn_global_load_lds((gu32*)(g0 + 4096),                    \
                                         (su32*)(l0 + 4096), 16, 0, 0);         \
        __builtin_amdgcn_global_load_lds((gu32*)(g0 + 5120),                    \
                                         (su32*)(l0 + 5120), 16, 0, 0);         \
        __builtin_amdgcn_global_load_lds((gu32*)(g0 + 6144),                    \
                                         (su32*)(l0 + 6144), 16, 0, 0);         \
        __builtin_amdgcn_global_load_lds((gu32*)(g0 + 7168),                    \
                                         (su32*)(l0 + 7168), 16, 0, 0);         \
    } while (0)

    unsigned rk[16];
#pragma unroll
    for (int s = 0; s < 16; ++s) rk[s] = 0xFFFFFFFFu;

    STAGE(0, 0);
    __syncthreads();                          // drains vmcnt: buf0 ready

#pragma unroll 1
    for (int st = 0; st < STEPS64; ++st) {
        int cur = st & 1;
        if (st < STEPS64 - 1) STAGE(st + 1, cur ^ 1);   // issue-early prefetch

#pragma unroll
        for (int ct = 0; ct < 4; ++ct) {
            // B fragments from LDS: kc at ct*8192 + kc*1024 + q*256 + tm*16
            const char* lb = &bbuf[cur][ct * 8192 + q * 256 + tm * 16];
            v8h bf[8];
#pragma unroll
            for (int kc = 0; kc < 8; ++kc) bf[kc] = *(const v8h*)(lb + kc * 1024);
            float enc = en_g[sp * 1024 + st * 64 + ct * 16 + tm];  // L2-hit

            v4f acc[4];
#pragma unroll
            for (int mi = 0; mi < 4; ++mi)
                acc[mi] = __builtin_amdgcn_mfma_f32_16x16x32_f16(zf[mi][0], bf[0], (v4f)0.f, 0, 0, 0);
#pragma unroll
            for (int kc = 1; kc < 8; ++kc)
#pragma unroll
                for (int mi = 0; mi < 4; ++mi)
                    acc[mi] = __builtin_amdgcn_mfma_f32_16x16x32_f16(zf[mi][kc], bf[kc], acc[mi], 0, 0, 0);

            unsigned tag = (unsigned)(st * 4 + ct);
            // packed-key argmin: fmaf + lshl_or + min_u32 per value
#pragma unroll
            for (int mi = 0; mi < 4; ++mi)
#pragma unroll
                for (int r = 0; r < 4; ++r) {
                    float s = fmaf(-2.f, acc[mi][r], enc);  // >0, in [512,131072)
                    unsigned key = (__float_as_uint(s) << 6) | tag;
                    int slot = mi * 4 + r;
                    rk[slot] = key < rk[slot] ? key : rk[slot];
                }
        }
        __syncthreads();   // next buf staged + all waves done reading cur buf
    }
#undef STAGE

    // ---- reduce across the 16 column-lanes (tm); write split winner ----
    // key ties (same value, same tag) break on lower tm -> lower code,
    // matching np.argmin first-min semantics.
#pragma unroll
    for (int slot = 0; slot < 16; ++slot) {
        unsigned k = rk[slot];
        int      t_ = tm;
#pragma unroll
        for (int m = 1; m <= 8; m <<= 1) {
            unsigned k2 = __shfl_xor(k, m, 64);
            int      t2 = __shfl_xor(t_, m, 64);
            if (k2 < k || (k2 == k && t2 < t_)) { k = k2; t_ = t2; }
        }
        if (tm == 0) {
            int row = r0 + (slot >> 2) * 16 + q * 4 + (slot & 3);
            int bi  = sp * 1024 + (int)(k & 63u) * 16 + t_;
            ((int*)(ws + WS_PI))[sp * MROWS + row] = bi;
            // exact reconstruction: all scores have float bits[31:26] == 17
            ((float*)(ws + WS_PD))[sp * MROWS + row] =
                __uint_as_float((k >> 6) | (17u << 26));
        }
    }
}

// ---------------------------------------------------------------------------
// Kernel 3: PRUNED exact fp32 re-rank + gather + STE output + 1.25*MSE loss.
// The prune invariant (since r5, always passing): pd > dmin + 0.75 =>
// cannot be the exact winner (0.75 >> 2x f16 dot error). Single-survivor
// fast path (r15, +3 us): if exactly one candidate survives, it IS the
// winner — skip the exact phase. Exact ties co-survive (pd differ by <=
// 2x error < 0.75), so the first-min tie-break path is preserved.
__global__ void rerank_out_kernel(const float* __restrict__ z,
                                  const float* __restrict__ emb,
                                  const char* __restrict__ ws,
                                  float* __restrict__ out) {
    __shared__ float wsum[4];
    const int*   pi = (const int*)(ws + WS_PI);
    const float* pd = (const float*)(ws + WS_PD);
    int tid = threadIdx.x, lane = tid & 63, w = tid >> 6;
    int g = lane >> 3, sub = lane & 7;    // candidate group, dim-slice
    const float4* e4 = (const float4*)emb;
    const float4* z4 = (const float4*)z;
    float lsum = 0.f;

#pragma unroll 1
    for (int it = 0; it < 4; ++it) {
        int row = it * 4096 + blockIdx.x * 4 + w;
        int ci   = pi[g * MROWS + row];
        float pg = pd[g * MROWS + row];
        // min approx distance across the 8 groups (pg uniform within group)
        float dmin = pg;
#pragma unroll
        for (int m = 8; m <= 32; m <<= 1) dmin = fminf(dmin, __shfl_xor(dmin, m, 64));

        bool alive = (pg <= dmin + 0.75f);
        unsigned long long mask = __ballot(alive);
        int di;
        if (__popcll(mask) == 8) {
            // exactly one surviving group (8 lanes) -> it is the exact winner
            di = __shfl(ci, __ffsll(mask) - 1, 64);
        } else {
            float s;
            if (alive) {
                // exact squared distance over dims [sub*32, sub*32+32)
                s = 0.f;
#pragma unroll
                for (int j = 0; j < 8; ++j) {
                    float4 ev = e4[(size_t)ci * 64 + sub * 8 + j];
                    float4 zv = z4[(size_t)row * 64 + sub * 8 + j];
                    float dx = ev.x - zv.x, dy = ev.y - zv.y;
                    float dz = ev.z - zv.z, dw = ev.w - zv.w;
                    s += dx * dx + dy * dy + dz * dz + dw * dw;
                }
            } else {
                s = 3e38f;   // pruned: cannot be the exact winner
            }
#pragma unroll
            for (int m = 1; m <= 4; m <<= 1) s += __shfl_xor(s, m, 64);
            // min over the 8 groups, lowest idx on ties (np first-min)
            float dv = s; di = ci;
#pragma unroll
            for (int m = 8; m <= 32; m <<= 1) {
                float d2 = __shfl_xor(dv, m, 64);
                int   i2 = __shfl_xor(di, m, 64);
                if (d2 < dv || (d2 == dv && i2 < di)) { dv = d2; di = i2; }
            }
        }
        if (lane == 0) out[IDXOFF + row] = (float)di;
        // gather winner, STE output, loss partial
        float4 qv = e4[(size_t)di * 64 + lane];
        float4 zv = z4[(size_t)row * 64 + lane];
        float dx = qv.x - zv.x, dy = qv.y - zv.y;
        float dz = qv.z - zv.z, dw = qv.w - zv.w;
        float4 o;   // match reference STE rounding: z + (q - z)
        o.x = zv.x + dx; o.y = zv.y + dy; o.z = zv.z + dz; o.w = zv.w + dw;
        ((float4*)out)[(size_t)row * 64 + lane] = o;
        lsum += dx * dx + dy * dy + dz * dz + dw * dw;
    }

#pragma unroll
    for (int m = 32; m >= 1; m >>= 1) lsum += __shfl_xor(lsum, m, 64);
    if (lane == 0) wsum[w] = lsum;
    __syncthreads();
    if (tid == 0)
        atomicAdd(out + LOSS_OFF,
                  (wsum[0] + wsum[1] + wsum[2] + wsum[3]) * (1.25f / 4194304.f));
}

// ---------------------------------------------------------------------------
extern "C" void kernel_launch(void* const* d_in, const int* in_sizes, int n_in,
                              void* d_out, int out_size, void* d_ws, size_t ws_size,
                              hipStream_t stream) {
    const float* z   = (const float*)d_in[0];
    const float* emb = (const float*)d_in[1];
    float* out = (float*)d_out;
    char*  ws  = (char*)d_ws;   // ~13.8 MB used

    hipLaunchKernelGGL(conv_kernel, dim3((MROWS + KCODES) * 32 / 256), dim3(256),
                       0, stream, z, emb, ws, out + LOSS_OFF);
    hipLaunchKernelGGL(vq_pass1_kernel, dim3((MROWS / 256) * NSPLIT), dim3(256),
                       0, stream, ws, ws);
    hipLaunchKernelGGL(rerank_out_kernel, dim3(1024), dim3(256),
                       0, stream, z, emb, ws, out);
}